// Round 3
// baseline (328.487 us; speedup 1.0000x reference)
//
#include <hip/hip_runtime.h>
#include <hip/hip_bf16.h>
#include <hip/hip_cooperative_groups.h>

namespace cg = cooperative_groups;

// Problem constants
#define B_ 4
#define S_ 2048
#define E_ 1024

// Tiling
#define NS 256                // s-chunks for column-sum partials (per b)
#define ROWS (S_ / NS)        // 8 rows per colsum block
#define RB 64                 // reduction chunks for each small GEMV
#define CW 16                 // chunk width (e's or j's per chunk)
#define RPB 8                 // rows written per broadcast block

// One cooperative kernel, 1024 blocks x 256 threads (4 blocks/CU).
// Phase 1: pv[b][ns][e] = colsum of 8 rows of value; o[b]=bo (ns==0)
// Phase 2: tpart[rb][b][j] = vbar_chunk[rb] @ Wv rows
// Phase 3: o[b][i] += t_chunk[rb] @ Wo rows   (atomicAdd)
// Phase 4: out[b][s][:] = o[b][:]
__global__ __launch_bounds__(256) void k_fused(
    const float* __restrict__ value,
    const float* __restrict__ Wv, const float* __restrict__ bv,
    const float* __restrict__ Wo, const float* __restrict__ bo,
    float* __restrict__ pv, float* __restrict__ tpart,
    float* __restrict__ o, float* __restrict__ out)
{
    const int bx = blockIdx.x;
    const int t  = threadIdx.x;
    const int b  = bx >> 8;
    cg::grid_group grid = cg::this_grid();

    __shared__ float red[16][CW];
    __shared__ float vb[CW];

    // -------- Phase 1: column sums of value --------
    {
        const int ns = bx & 255;
        const float4* src = reinterpret_cast<const float4*>(
            value + ((size_t)b * S_ + (size_t)ns * ROWS) * E_);
        float4 acc = make_float4(0.f, 0.f, 0.f, 0.f);
#pragma unroll
        for (int r = 0; r < ROWS; ++r) {
            float4 v = src[r * (E_ / 4) + t];
            acc.x += v.x; acc.y += v.y; acc.z += v.z; acc.w += v.w;
        }
        reinterpret_cast<float4*>(pv + ((size_t)b * NS + ns) * E_)[t] = acc;
        if (ns == 0) {
            reinterpret_cast<float4*>(o + (size_t)b * E_)[t] =
                reinterpret_cast<const float4*>(bo)[t];
        }
    }
    grid.sync();

    // -------- Phase 2: tpart[rb][b][j] --------
    {
        const int js = bx & 3, rb = (bx >> 2) & 63;
        const int e_l = t & 15, g = t >> 4;
        float s = 0.f;
        for (int ns = g; ns < NS; ns += 16)
            s += pv[((size_t)b * NS + ns) * E_ + rb * CW + e_l];
        red[g][e_l] = s;
        __syncthreads();
        if (t < CW) {
            float v = 0.f;
#pragma unroll
            for (int gg = 0; gg < 16; ++gg) v += red[gg][t];
            vb[t] = v;
        }
        __syncthreads();
        const int j = js * 256 + t;
        const float* w = Wv + (size_t)(rb * CW) * E_ + j;
        float acc = 0.f;
#pragma unroll
        for (int k = 0; k < CW; ++k)
            acc = fmaf(vb[k], w[(size_t)k * E_], acc);
        tpart[((size_t)rb * B_ + b) * E_ + j] = acc;
    }
    grid.sync();

    // -------- Phase 3: o[b][i] += tpart-chunk @ Wo --------
    {
        const int is = bx & 3, rb = (bx >> 2) & 63;
        const int j_l = t & 15, g = t >> 4;
        float s = 0.f;
#pragma unroll
        for (int p = g; p < RB; p += 16)
            s += tpart[((size_t)p * B_ + b) * E_ + rb * CW + j_l];
        red[g][j_l] = s;
        __syncthreads();
        if (t < CW) {
            float v = (float)S_ * bv[rb * CW + t];
#pragma unroll
            for (int gg = 0; gg < 16; ++gg) v += red[gg][t];
            vb[t] = v;
        }
        __syncthreads();
        const int i = is * 256 + t;
        const float* w = Wo + (size_t)(rb * CW) * E_ + i;
        float acc = 0.f;
#pragma unroll
        for (int k = 0; k < CW; ++k)
            acc = fmaf(vb[k], w[(size_t)k * E_], acc);
        atomicAdd(&o[(size_t)b * E_ + i], acc);
    }
    grid.sync();

    // -------- Phase 4: broadcast o over s --------
    {
        const int sb = bx & 255;
        float4 ov = reinterpret_cast<const float4*>(o + (size_t)b * E_)[t];
        float4* dst = reinterpret_cast<float4*>(
            out + ((size_t)b * S_ + (size_t)sb * RPB) * E_);
#pragma unroll
        for (int r = 0; r < RPB; ++r)
            dst[r * (E_ / 4) + t] = ov;
    }
}

// ---------------------------------------------------------------------------
extern "C" void kernel_launch(void* const* d_in, const int* in_sizes, int n_in,
                              void* d_out, int out_size, void* d_ws, size_t ws_size,
                              hipStream_t stream) {
    // setup_inputs order: query, key, value, Wq, bq, Wk, bk, Wv, bv, Wo, bo
    const float* value = (const float*)d_in[2];
    const float* Wv    = (const float*)d_in[7];
    const float* bv    = (const float*)d_in[8];
    const float* Wo    = (const float*)d_in[9];
    const float* bo    = (const float*)d_in[10];
    float* out = (float*)d_out;

    float* pv    = (float*)d_ws;                       // [B][NS][E]   4 MB
    float* tpart = pv + (size_t)B_ * NS * E_;          // [RB][B][E]   1 MB
    float* o     = tpart + (size_t)RB * B_ * E_;       // [B][E]       16 KB

    void* args[] = { (void*)&value, (void*)&Wv, (void*)&bv, (void*)&Wo,
                     (void*)&bo, (void*)&pv, (void*)&tpart, (void*)&o,
                     (void*)&out };
    hipLaunchCooperativeKernel((const void*)k_fused, dim3(B_ * NS), dim3(256),
                               args, 0, stream);
}

// Round 4
// 48.612 us; speedup vs baseline: 6.7573x; 6.7573x over previous
//
#include <hip/hip_runtime.h>
#include <hip/hip_bf16.h>

// Problem constants
#define B_ 4
#define S_ 2048
#define E_ 1024

// Tiling
#define NSB 128               // colsum blocks per batch
#define ROWS1 (S_ / NSB)      // 16 rows per colsum block
#define RPB 8                 // rows written per broadcast block

// ---------------------------------------------------------------------------
// K1: vbar[b][e] += colsum of 16 rows of value   (atomicAdd, vbar pre-zeroed)
// grid (NSB, B_), 256 threads, float4 per thread covers full E row.
// ---------------------------------------------------------------------------
__global__ __launch_bounds__(256) void k_colsum(const float* __restrict__ value,
                                                float* __restrict__ vbar) {
    const int ns = blockIdx.x, b = blockIdx.y;
    const int t = threadIdx.x;
    const float4* src = reinterpret_cast<const float4*>(
        value + ((size_t)b * S_ + (size_t)ns * ROWS1) * E_);
    float4 acc = make_float4(0.f, 0.f, 0.f, 0.f);
#pragma unroll
    for (int r = 0; r < ROWS1; ++r) {
        float4 v = src[r * (E_ / 4) + t];
        acc.x += v.x; acc.y += v.y; acc.z += v.z; acc.w += v.w;
    }
    float* dst = vbar + (size_t)b * E_ + t * 4;
    atomicAdd(dst + 0, acc.x);
    atomicAdd(dst + 1, acc.y);
    atomicAdd(dst + 2, acc.z);
    atomicAdd(dst + 3, acc.w);
}

// ---------------------------------------------------------------------------
// K2: merged middle. Block (rb, b):
//   tj[0..15] = vbar[b] @ Wv[:, rb*16..+16] + S*bv[chunk]
//   o[b][:]  += tj @ Wo[rb*16..+16, :]       (atomicAdd, o pre-zeroed)
// grid (64, B_) = 256 blocks, 256 threads.
// ---------------------------------------------------------------------------
__global__ __launch_bounds__(256) void k_mid(const float* __restrict__ vbar,
                                             const float* __restrict__ Wv,
                                             const float* __restrict__ bv,
                                             const float* __restrict__ Wo,
                                             float* __restrict__ o) {
    const int rb = blockIdx.x, b = blockIdx.y;
    const int t = threadIdx.x;
    __shared__ float vb[E_];
    __shared__ float red[16][16];
    __shared__ float tj[16];

    reinterpret_cast<float4*>(vb)[t] =
        reinterpret_cast<const float4*>(vbar + (size_t)b * E_)[t];
    __syncthreads();

    // Phase B: 16-wide t-chunk, split reduction over e (16 groups x 64 e's)
    const int j_l = t & 15, g = t >> 4;
    const int j = rb * 16 + j_l;
    float acc = 0.f;
#pragma unroll 8
    for (int e = g; e < E_; e += 16)
        acc = fmaf(vb[e], Wv[(size_t)e * E_ + j], acc);
    red[g][j_l] = acc;
    __syncthreads();
    if (t < 16) {
        float v = (float)S_ * bv[rb * 16 + t];
#pragma unroll
        for (int gg = 0; gg < 16; ++gg) v += red[gg][t];
        tj[t] = v;
    }
    __syncthreads();

    // Phase C: o[b][i] += sum_j tj[j] * Wo[rb*16+j][i], i = k*256 + t
    float oacc[4] = {0.f, 0.f, 0.f, 0.f};
#pragma unroll
    for (int jj = 0; jj < 16; ++jj) {
        const float* wo = Wo + (size_t)(rb * 16 + jj) * E_;
        const float tv = tj[jj];
#pragma unroll
        for (int k2 = 0; k2 < 4; ++k2)
            oacc[k2] = fmaf(tv, wo[k2 * 256 + t], oacc[k2]);
    }
#pragma unroll
    for (int k2 = 0; k2 < 4; ++k2)
        atomicAdd(&o[(size_t)b * E_ + k2 * 256 + t], oacc[k2]);
}

// ---------------------------------------------------------------------------
// K3: out[b][s][:] = o[b][:] + bo[:]  broadcast over s.
// grid (S_/RPB, B_), 256 threads, float4 per thread covers full row.
// ---------------------------------------------------------------------------
__global__ __launch_bounds__(256) void k_bcast(const float* __restrict__ o,
                                               const float* __restrict__ bo,
                                               float* __restrict__ out) {
    const int sb = blockIdx.x, b = blockIdx.y;
    const int t = threadIdx.x;
    float4 ov = reinterpret_cast<const float4*>(o + (size_t)b * E_)[t];
    float4 bb = reinterpret_cast<const float4*>(bo)[t];
    ov.x += bb.x; ov.y += bb.y; ov.z += bb.z; ov.w += bb.w;
    float4* dst = reinterpret_cast<float4*>(
        out + ((size_t)b * S_ + (size_t)sb * RPB) * E_);
#pragma unroll
    for (int r = 0; r < RPB; ++r)
        dst[r * (E_ / 4) + t] = ov;
}

// ---------------------------------------------------------------------------
extern "C" void kernel_launch(void* const* d_in, const int* in_sizes, int n_in,
                              void* d_out, int out_size, void* d_ws, size_t ws_size,
                              hipStream_t stream) {
    // setup_inputs order: query, key, value, Wq, bq, Wk, bk, Wv, bv, Wo, bo
    const float* value = (const float*)d_in[2];
    const float* Wv    = (const float*)d_in[7];
    const float* bv    = (const float*)d_in[8];
    const float* Wo    = (const float*)d_in[9];
    const float* bo    = (const float*)d_in[10];
    float* out = (float*)d_out;

    float* vbar = (float*)d_ws;                 // [B][E]  16 KB
    float* o    = vbar + (size_t)B_ * E_;       // [B][E]  16 KB

    hipMemsetAsync(d_ws, 0, 2 * (size_t)B_ * E_ * sizeof(float), stream);
    k_colsum<<<dim3(NSB, B_),      256, 0, stream>>>(value, vbar);
    k_mid   <<<dim3(E_ / 16, B_),  256, 0, stream>>>(vbar, Wv, bv, Wo, o);
    k_bcast <<<dim3(S_ / RPB, B_), 256, 0, stream>>>(o, bo, out);
}

// Round 5
// 36.158 us; speedup vs baseline: 9.0847x; 1.3444x over previous
//
#include <hip/hip_runtime.h>
#include <hip/hip_bf16.h>

// Problem constants
#define B_ 4
#define S_ 2048
#define E_ 1024

// Tiling
#define NS 128                // colsum partials per batch
#define ROWS1 (S_ / NS)       // 16 rows per colsum block
#define RPB 8                 // rows written per broadcast block

// ---------------------------------------------------------------------------
// K1: pv[b][ns][e] = colsum of 16 rows of value (plain stores).
// ns==0 block also inits o[b][:] = bo[:] for K2's atomic accumulation.
// grid (NS, B_) = 512 blocks, 256 threads, float4 covers full E row.
// ---------------------------------------------------------------------------
__global__ __launch_bounds__(256) void k_colsum(const float* __restrict__ value,
                                                const float* __restrict__ bo,
                                                float* __restrict__ pv,
                                                float* __restrict__ o) {
    const int ns = blockIdx.x, b = blockIdx.y;
    const int t = threadIdx.x;
    const float4* src = reinterpret_cast<const float4*>(
        value + ((size_t)b * S_ + (size_t)ns * ROWS1) * E_);
    float4 acc = make_float4(0.f, 0.f, 0.f, 0.f);
#pragma unroll
    for (int r = 0; r < ROWS1; ++r) {
        float4 v = src[r * (E_ / 4) + t];
        acc.x += v.x; acc.y += v.y; acc.z += v.z; acc.w += v.w;
    }
    reinterpret_cast<float4*>(pv + ((size_t)b * NS + ns) * E_)[t] = acc;
    if (ns == 0) {
        reinterpret_cast<float4*>(o + (size_t)b * E_)[t] =
            reinterpret_cast<const float4*>(bo)[t];
    }
}

// ---------------------------------------------------------------------------
// K2: merged middle. Block (rb, b), rb over 64 j-chunks of 16:
//   vb[:]     = sum_ns pv[b][ns][:]                  (LDS, coalesced)
//   tj[0..15] = vb @ Wv[:, rb*16..+16] + S*bv[chunk]
//   o[b][:]  += tj @ Wo[rb*16..+16, :]               (atomicAdd, 64-way)
// grid (64, B_) = 256 blocks, 256 threads.
// ---------------------------------------------------------------------------
__global__ __launch_bounds__(256) void k_mid(const float* __restrict__ pv,
                                             const float* __restrict__ Wv,
                                             const float* __restrict__ bv,
                                             const float* __restrict__ Wo,
                                             float* __restrict__ o) {
    const int rb = blockIdx.x, b = blockIdx.y;
    const int t = threadIdx.x;
    __shared__ float vb[E_];
    __shared__ float red[16][16];
    __shared__ float tj[16];

    // Stage vbar: thread t owns float4 column t (coalesced over ns).
    {
        float4 a = make_float4(0.f, 0.f, 0.f, 0.f);
        const float4* p = reinterpret_cast<const float4*>(pv + (size_t)b * NS * E_);
#pragma unroll 4
        for (int ns = 0; ns < NS; ++ns) {
            float4 v = p[ns * (E_ / 4) + t];
            a.x += v.x; a.y += v.y; a.z += v.z; a.w += v.w;
        }
        reinterpret_cast<float4*>(vb)[t] = a;
    }
    __syncthreads();

    // GEMV1 chunk: 16 j's, split reduction over e (16 groups x 64 e's).
    const int j_l = t & 15, g = t >> 4;
    const int j = rb * 16 + j_l;
    float acc = 0.f;
#pragma unroll 8
    for (int e = g; e < E_; e += 16)
        acc = fmaf(vb[e], Wv[(size_t)e * E_ + j], acc);
    red[g][j_l] = acc;
    __syncthreads();
    if (t < 16) {
        float v = (float)S_ * bv[rb * 16 + t];
#pragma unroll
        for (int gg = 0; gg < 16; ++gg) v += red[gg][t];
        tj[t] = v;
    }
    __syncthreads();

    // GEMV2 contribution: o[b][i] += sum_j tj[j] * Wo[rb*16+j][i].
    float oacc[4] = {0.f, 0.f, 0.f, 0.f};
#pragma unroll
    for (int jj = 0; jj < 16; ++jj) {
        const float* wo = Wo + (size_t)(rb * 16 + jj) * E_;
        const float tv = tj[jj];
#pragma unroll
        for (int k2 = 0; k2 < 4; ++k2)
            oacc[k2] = fmaf(tv, wo[k2 * 256 + t], oacc[k2]);
    }
#pragma unroll
    for (int k2 = 0; k2 < 4; ++k2)
        atomicAdd(&o[(size_t)b * E_ + k2 * 256 + t], oacc[k2]);
}

// ---------------------------------------------------------------------------
// K3: out[b][s][:] = o[b][:]  broadcast over s.
// grid (S_/RPB, B_) = 1024 blocks, 256 threads.
// ---------------------------------------------------------------------------
__global__ __launch_bounds__(256) void k_bcast(const float* __restrict__ o,
                                               float* __restrict__ out) {
    const int sb = blockIdx.x, b = blockIdx.y;
    const int t = threadIdx.x;
    float4 ov = reinterpret_cast<const float4*>(o + (size_t)b * E_)[t];
    float4* dst = reinterpret_cast<float4*>(
        out + ((size_t)b * S_ + (size_t)sb * RPB) * E_);
#pragma unroll
    for (int r = 0; r < RPB; ++r)
        dst[r * (E_ / 4) + t] = ov;
}

// ---------------------------------------------------------------------------
extern "C" void kernel_launch(void* const* d_in, const int* in_sizes, int n_in,
                              void* d_out, int out_size, void* d_ws, size_t ws_size,
                              hipStream_t stream) {
    // setup_inputs order: query, key, value, Wq, bq, Wk, bk, Wv, bv, Wo, bo
    const float* value = (const float*)d_in[2];
    const float* Wv    = (const float*)d_in[7];
    const float* bv    = (const float*)d_in[8];
    const float* Wo    = (const float*)d_in[9];
    const float* bo    = (const float*)d_in[10];
    float* out = (float*)d_out;

    float* pv = (float*)d_ws;                  // [B][NS][E]  2 MB
    float* o  = pv + (size_t)B_ * NS * E_;     // [B][E]      16 KB

    k_colsum<<<dim3(NS, B_),       256, 0, stream>>>(value, bo, pv, o);
    k_mid   <<<dim3(E_ / 16, B_),  256, 0, stream>>>(pv, Wv, bv, Wo, o);
    k_bcast <<<dim3(S_ / RPB, B_), 256, 0, stream>>>(o, out);
}

// Round 6
// 26.639 us; speedup vs baseline: 12.3313x; 1.3574x over previous
//
#include <hip/hip_runtime.h>
#include <hip/hip_bf16.h>

// Problem constants
#define B_ 4
#define S_ 2048
#define E_ 1024

// k_front tiling
#define ES 16                 // e-slices of 64
#define SC 4                  // s-chunks of 512
#define EPS (E_ / ES)         // 64 e's per slice
#define SPC (S_ / SC)         // 512 rows per chunk
#define NPART (ES * SC)       // 64 t-partials per (b)

// k_bcast tiling
#define RPB 8                 // rows written per broadcast block

// ---------------------------------------------------------------------------
// K1: fused colsum + GEMV1 split-k.
// Block (es, sc, b), 1024 threads:
//   vbs[64] = sum over s-chunk of value[b][s][e-slice]     (LDS reduce)
//   tpart[es*SC+sc][b][j] = sum_{e in slice} vbs[e] * Wv[e][j]  (plain store)
// Block (0,0,b) also inits o[b][:] = bo[:].
// grid (ES, SC, B_) = 256 blocks, 1024 threads (16 waves/CU).
// ---------------------------------------------------------------------------
__global__ __launch_bounds__(1024) void k_front(const float* __restrict__ value,
                                                const float* __restrict__ Wv,
                                                const float* __restrict__ bo,
                                                float* __restrict__ tpart,
                                                float* __restrict__ o) {
    const int es = blockIdx.x, sc = blockIdx.y, b = blockIdx.z;
    const int t = threadIdx.x;
    __shared__ float4 red[64][16];
    __shared__ float4 red2[4][16];
    __shared__ float vb[EPS];

    // Phase A: column-sum the value tile [512 s][64 e].
    // thread: c4 = float4-column within slice, rg = row group (8 rows each).
    {
        const int c4 = t & 15, rg = t >> 4;
        const float* base = value + ((size_t)b * S_ + (size_t)sc * SPC) * E_
                            + es * EPS + c4 * 4;
        float4 acc = make_float4(0.f, 0.f, 0.f, 0.f);
#pragma unroll
        for (int r = 0; r < 8; ++r) {
            float4 v = *reinterpret_cast<const float4*>(base + (size_t)(rg + r * 64) * E_);
            acc.x += v.x; acc.y += v.y; acc.z += v.z; acc.w += v.w;
        }
        red[rg][c4] = acc;
    }
    __syncthreads();
    if (t < 64) {
        const int c = t & 15, q = t >> 4;
        float4 s = make_float4(0.f, 0.f, 0.f, 0.f);
#pragma unroll
        for (int k = 0; k < 16; ++k) {
            float4 v = red[q * 16 + k][c];
            s.x += v.x; s.y += v.y; s.z += v.z; s.w += v.w;
        }
        red2[q][c] = s;
    }
    __syncthreads();
    if (t < 16) {
        float4 s0 = red2[0][t], s1 = red2[1][t], s2 = red2[2][t], s3 = red2[3][t];
        float4 s = make_float4(s0.x + s1.x + s2.x + s3.x,
                               s0.y + s1.y + s2.y + s3.y,
                               s0.z + s1.z + s2.z + s3.z,
                               s0.w + s1.w + s2.w + s3.w);
        reinterpret_cast<float4*>(vb)[t] = s;
    }
    __syncthreads();

    // Phase B: t-partial over the 64 Wv rows of this e-slice; j = t.
    {
        const float* wv = Wv + (size_t)(es * EPS) * E_ + t;
        float a = 0.f;
#pragma unroll 8
        for (int k = 0; k < EPS; ++k)
            a = fmaf(vb[k], wv[(size_t)k * E_], a);
        tpart[((size_t)(es * SC + sc) * B_ + b) * E_ + t] = a;
    }

    // o init for K2's atomics.
    if (es == 0 && sc == 0 && t < 256) {
        reinterpret_cast<float4*>(o + (size_t)b * E_)[t] =
            reinterpret_cast<const float4*>(bo)[t];
    }
}

// ---------------------------------------------------------------------------
// K2: reduce t-partials + bias, then Wo row-panel -> o via 64-way atomics.
// Block (jb, b): tj[0..15] = S*bv + sum_p tpart[p][b][jb*16..+16];
//                o[b][i] += sum_j tj[j] * Wo[jb*16+j][i]
// grid (64, B_) = 256 blocks, 256 threads.
// ---------------------------------------------------------------------------
__global__ __launch_bounds__(256) void k_mid(const float* __restrict__ tpart,
                                             const float* __restrict__ bv,
                                             const float* __restrict__ Wo,
                                             float* __restrict__ o) {
    const int jb = blockIdx.x, b = blockIdx.y;
    const int t = threadIdx.x;
    __shared__ float red[16][16];
    __shared__ float tj[16];

    {
        const int jl = t & 15, pg = t >> 4;
        float s = 0.f;
#pragma unroll
        for (int q = 0; q < 4; ++q) {
            const int p = pg + q * 16;
            s += tpart[((size_t)p * B_ + b) * E_ + jb * 16 + jl];
        }
        red[pg][jl] = s;
    }
    __syncthreads();
    if (t < 16) {
        float v = (float)S_ * bv[jb * 16 + t];
#pragma unroll
        for (int g = 0; g < 16; ++g) v += red[g][t];
        tj[t] = v;
    }
    __syncthreads();

    float oacc[4] = {0.f, 0.f, 0.f, 0.f};
#pragma unroll
    for (int jj = 0; jj < 16; ++jj) {
        const float* wo = Wo + (size_t)(jb * 16 + jj) * E_;
        const float tv = tj[jj];
#pragma unroll
        for (int k2 = 0; k2 < 4; ++k2)
            oacc[k2] = fmaf(tv, wo[k2 * 256 + t], oacc[k2]);
    }
#pragma unroll
    for (int k2 = 0; k2 < 4; ++k2)
        atomicAdd(&o[(size_t)b * E_ + k2 * 256 + t], oacc[k2]);
}

// ---------------------------------------------------------------------------
// K3: out[b][s][:] = o[b][:]  broadcast over s.
// grid (S_/RPB, B_) = 1024 blocks, 256 threads.
// ---------------------------------------------------------------------------
__global__ __launch_bounds__(256) void k_bcast(const float* __restrict__ o,
                                               float* __restrict__ out) {
    const int sb = blockIdx.x, b = blockIdx.y;
    const int t = threadIdx.x;
    float4 ov = reinterpret_cast<const float4*>(o + (size_t)b * E_)[t];
    float4* dst = reinterpret_cast<float4*>(
        out + ((size_t)b * S_ + (size_t)sb * RPB) * E_);
#pragma unroll
    for (int r = 0; r < RPB; ++r)
        dst[r * (E_ / 4) + t] = ov;
}

// ---------------------------------------------------------------------------
extern "C" void kernel_launch(void* const* d_in, const int* in_sizes, int n_in,
                              void* d_out, int out_size, void* d_ws, size_t ws_size,
                              hipStream_t stream) {
    // setup_inputs order: query, key, value, Wq, bq, Wk, bk, Wv, bv, Wo, bo
    const float* value = (const float*)d_in[2];
    const float* Wv    = (const float*)d_in[7];
    const float* bv    = (const float*)d_in[8];
    const float* Wo    = (const float*)d_in[9];
    const float* bo    = (const float*)d_in[10];
    float* out = (float*)d_out;

    float* tpart = (float*)d_ws;                       // [64][B][E]  1 MB
    float* o     = tpart + (size_t)NPART * B_ * E_;    // [B][E]      16 KB

    k_front<<<dim3(ES, SC, B_),    1024, 0, stream>>>(value, Wv, bo, tpart, o);
    k_mid  <<<dim3(NPART, B_),     256,  0, stream>>>(tpart, bv, Wo, o);
    k_bcast<<<dim3(S_ / RPB, B_),  256,  0, stream>>>(o, out);
}